// Round 2
// baseline (249.898 us; speedup 1.0000x reference)
//
#include <hip/hip_runtime.h>
#include <math.h>

// Sampler: temperature 0.8, top-k (k=50 input), top-p 0.9, inverse-CDF
// multinomial. B=128 rows, V=128000, fp32 logits -> int32 ids.
//
// Two-kernel structure:
//  K1 (scan): 128 rows x SLICES blocks, 256 thr, no LDS. Streams float4,
//     pushes candidates y >= YTH (x >= 14) to global per-row lists in d_ws.
//     Rationale: if |{y>=YTH}| >= k then top-k (plus kth ties) is a subset of
//     the candidate set, so no histogram is needed. Expected ~327 cands/row.
//  K2 (select): 1 block/row, 256 thr. Exact rank sort of candidates by
//     (x desc, idx asc) == jnp.argsort(-x) stability, then serial fp32
//     softmax / top-p / inverse-CDF tail (identical to the absmax-0 R1 code).
//     Fallback (count < k or > cap): exact kth value via 32-step binary
//     search on float key bits + rescan. Never triggers on this data.

#define CAP   1024     // candidate capacity per row (== MSORT)
#define MSORT 1024
#define SLICES 8

__device__ __forceinline__ unsigned fkey(float y) {
    unsigned b = __float_as_uint(y);
    return (b & 0x80000000u) ? ~b : (b | 0x80000000u);  // monotone: y asc -> key asc
}

// ---------------- Kernel 1: streaming candidate scan ----------------
__global__ __launch_bounds__(256)
void scan_kernel(const float* __restrict__ logits, int V,
                 int* __restrict__ cnts,
                 float* __restrict__ cy, int* __restrict__ ci)
{
    constexpr float YTH = 11.2f;   // x = 14.0
    const int tid = threadIdx.x;
    const int row = blockIdx.x / SLICES;
    const int sl  = blockIdx.x % SLICES;

    const float* rowp = logits + (size_t)row * (size_t)V;
    const float4* rp4 = (const float4*)rowp;
    const int n4 = V >> 2;
    const int per = (n4 + SLICES - 1) / SLICES;
    const int s0 = sl * per;
    const int s1 = min(s0 + per, n4);

    float* cyr = cy + (size_t)row * CAP;
    int*   cir = ci + (size_t)row * CAP;

    for (int i = s0 + tid; i < s1; i += 256) {
        float4 v = rp4[i];
        float ys[4] = {v.x, v.y, v.z, v.w};
#pragma unroll
        for (int c = 0; c < 4; ++c) {
            float y = ys[c];
            if (y >= YTH) {
                int p = atomicAdd(&cnts[row], 1);
                if (p < CAP) { cyr[p] = y; cir[p] = i * 4 + c; }
            }
        }
    }
    if (sl == SLICES - 1) {  // scalar tail if V % 4 != 0
        for (int i = (n4 << 2) + tid; i < V; i += 256) {
            float y = rowp[i];
            if (y >= YTH) {
                int p = atomicAdd(&cnts[row], 1);
                if (p < CAP) { cyr[p] = y; cir[p] = i; }
            }
        }
    }
}

// ---------------- Kernel 2: per-row selection + sampling ----------------
__global__ __launch_bounds__(256)
void select_kernel(const float* __restrict__ logits,
                   const float* __restrict__ uvec,
                   const int* __restrict__ topk_p,
                   const int* __restrict__ cnts,
                   const float* __restrict__ cy, const int* __restrict__ ci,
                   int* __restrict__ out, int V)
{
    constexpr float TEMP = 0.8f;
    constexpr float TOPP = 0.9f;

    __shared__ float sv[MSORT];     // x values
    __shared__ int   si[MSORT];
    __shared__ float ssv[MSORT];    // sorted desc by x (tie: idx asc)
    __shared__ int   ssi[MSORT];
    __shared__ float se[MSORT];     // exp(x - max)
    __shared__ float sq[MSORT];     // final probs, vocab order
    __shared__ int   sidx2[MSORT];
    __shared__ int   scount, cnt_sh;
    __shared__ int   L_sh;
    __shared__ float sum2_sh;

    const int tid = threadIdx.x;
    const int row = blockIdx.x;
    const int nth = blockDim.x;
    const int k_in = *topk_p;

    const float* rowp = logits + (size_t)row * (size_t)V;
    const float* cyr = cy + (size_t)row * CAP;
    const int*   cir = ci + (size_t)row * CAP;
    const int cnt = cnts[row];

    int M;
    if (cnt >= k_in && cnt <= CAP) {
        // ---- fast path: candidate list from K1 ----
        for (int i = tid; i < cnt; i += nth) {
            sv[i] = cyr[i] / TEMP;
            si[i] = cir[i];
        }
        M = cnt;
        __syncthreads();
    } else {
        // ---- slow fallback: exact kth value by binary search on key bits ----
        if (tid == 0) scount = 0;
        __syncthreads();
        unsigned lo = 0;
        for (int bit = 31; bit >= 0; --bit) {
            unsigned t = lo | (1u << bit);
            int local = 0;
            for (int i = tid; i < V; i += nth) local += (fkey(rowp[i]) >= t);
            if (tid == 0) cnt_sh = 0;
            __syncthreads();
            atomicAdd(&cnt_sh, local);
            __syncthreads();
            if (cnt_sh >= k_in) lo = t;
            __syncthreads();
        }
        // select all y with key >= lo  (== x >= kth, incl. ties)
        for (int i = tid; i < V; i += nth) {
            float y = rowp[i];
            if (fkey(y) >= lo) {
                int p = atomicAdd(&scount, 1);
                if (p < MSORT) { sv[p] = y / TEMP; si[p] = i; }
            }
        }
        __syncthreads();
        M = min(scount, MSORT);
    }

    // ---- exact rank sort: x desc, tie idx asc (matches argsort(-x)) ----
    for (int i = tid; i < M; i += nth) {
        float v = sv[i]; int ix = si[i];
        int r = 0;
        for (int j = 0; j < M; ++j) {
            float vj = sv[j];
            if (vj > v || (vj == v && si[j] < ix)) ++r;
        }
        ssv[r] = v; ssi[r] = ix;
    }
    __syncthreads();

    const float mm = (M > 0) ? ssv[0] : 0.0f;
    for (int i = tid; i < M; i += nth) se[i] = expf(ssv[i] - mm);
    __syncthreads();

    // ---- serial tiny tail: top-k ties, softmax, top-p prefix cut ----
    if (tid == 0) {
        int L = 0;
        if (M > 0) {
            int kk = k_in; if (kk > M) kk = M; if (kk < 1) kk = 1;
            float kth = ssv[kk - 1];
            int Kp = kk;
            while (Kp < M && ssv[Kp] == kth) ++Kp;   // keep ties with kth
            float sum1 = 0.0f;
            for (int i = 0; i < Kp; ++i) sum1 += se[i];
            float cdf = 0.0f;
            for (int i = 0; i < Kp; ++i) {
                if (i > 0 && cdf > TOPP) break;      // remove iff cdf[i-1] > p
                L = i + 1;
                cdf += se[i] / sum1;
            }
            float sum2 = 0.0f;
            for (int i = 0; i < L; ++i) sum2 += se[i];
            sum2_sh = sum2;
        } else {
            sum2_sh = 1.0f;
        }
        L_sh = L;
    }
    __syncthreads();
    const int L = L_sh;
    const float sum2 = sum2_sh;

    // ---- reorder kept entries by vocab index, final probs ----
    if (tid < L) {
        int ix = ssi[tid];
        int r = 0;
        for (int j = 0; j < L; ++j) r += (ssi[j] < ix);
        sidx2[r] = ix;
        sq[r] = se[tid] / sum2;
    }
    __syncthreads();

    // ---- inverse-CDF sample: count(csum <= u) = first idx with cum > u ----
    if (tid == 0) {
        float uu = uvec[row];
        float cum = 0.0f;
        int ans = V;                     // u >= total -> count is V
        for (int i = 0; i < L; ++i) {
            cum += sq[i];
            if (cum > uu) { ans = sidx2[i]; break; }
        }
        out[row] = ans;
    }
}

// ---------------- Fallback monolithic kernel (R1, used only if ws too small) --
#define NBINS 2048
#define CAND_CAP 8192

__global__ __launch_bounds__(1024)
void sampler_mono_kernel(const float* __restrict__ logits,
                         const float* __restrict__ uvec,
                         const int* __restrict__ topk_p,
                         int* __restrict__ out, int V)
{
    constexpr float YLO    = 6.4f;
    constexpr float BININV = 160.0f;
    constexpr float YCTH   = 8.8f;
    constexpr float TEMP   = 0.8f;
    constexpr float TOPP   = 0.9f;
    constexpr int   BSAFE  = 386;

    __shared__ int   hist[NBINS];
    __shared__ float cval[CAND_CAP];
    __shared__ int   cidx[CAND_CAP];
    __shared__ int   suf[1024];
    __shared__ float sv[MSORT];
    __shared__ int   si[MSORT];
    __shared__ float ssv[MSORT];
    __shared__ int   ssi[MSORT];
    __shared__ float se[MSORT];
    __shared__ float sq[MSORT];
    __shared__ int   sidx2[MSORT];
    __shared__ int   ccount, scount, bstar, fastpath;
    __shared__ int   L_sh;
    __shared__ float sum2_sh;

    const int tid = threadIdx.x;
    const int row = blockIdx.x;
    const int nth = blockDim.x;

    for (int i = tid; i < NBINS; i += nth) hist[i] = 0;
    if (tid == 0) { ccount = 0; scount = 0; bstar = -1; }
    __syncthreads();

    const float* rowp = logits + (size_t)row * (size_t)V;
    const float4* rp4 = (const float4*)rowp;
    const int n4 = V >> 2;

    for (int i = tid; i < n4; i += nth) {
        float4 v = rp4[i];
        float ys[4] = {v.x, v.y, v.z, v.w};
#pragma unroll
        for (int c = 0; c < 4; ++c) {
            float y = ys[c];
            float fb = (y - YLO) * BININV;
            if (fb >= 0.0f) {
                int b = (int)floorf(fb);
                if (b >= NBINS) b = NBINS - 1;
                atomicAdd(&hist[b], 1);
                if (y >= YCTH) {
                    int p = atomicAdd(&ccount, 1);
                    if (p < CAND_CAP) { cval[p] = y; cidx[p] = i * 4 + c; }
                }
            }
        }
    }
    for (int i = (n4 << 2) + tid; i < V; i += nth) {
        float y = rowp[i];
        float fb = (y - YLO) * BININV;
        if (fb >= 0.0f) {
            int b = (int)floorf(fb);
            if (b >= NBINS) b = NBINS - 1;
            atomicAdd(&hist[b], 1);
            if (y >= YCTH) {
                int p = atomicAdd(&ccount, 1);
                if (p < CAND_CAP) { cval[p] = y; cidx[p] = i; }
            }
        }
    }
    __syncthreads();

    const int k_in = *topk_p;

    {
        int g = hist[2 * tid] + hist[2 * tid + 1];
        suf[tid] = g;
        __syncthreads();
        for (int off = 1; off < 1024; off <<= 1) {
            int v = suf[tid];
            int add = (tid + off < 1024) ? suf[tid + off] : 0;
            __syncthreads();
            suf[tid] = v + add;
            __syncthreads();
        }
        int s_t = suf[tid];
        int s_n = (tid + 1 < 1024) ? suf[tid + 1] : 0;
        if (s_t >= k_in && s_n < k_in) {
            int suf_hi = s_n + hist[2 * tid + 1];
            bstar = (suf_hi >= k_in) ? (2 * tid + 1) : (2 * tid);
        }
    }
    __syncthreads();
    if (tid == 0) {
        if (bstar < 0) bstar = 0;
        fastpath = (ccount <= CAND_CAP) && (bstar >= BSAFE);
    }
    __syncthreads();

    const int blo = (bstar > 0) ? (bstar - 1) : 0;
    if (fastpath) {
        int nc = min(ccount, CAND_CAP);
        for (int p = tid; p < nc; p += nth) {
            float y = cval[p];
            int b = (int)floorf((y - YLO) * BININV);
            if (b >= NBINS) b = NBINS - 1;
            if (b >= blo) {
                int pos = atomicAdd(&scount, 1);
                if (pos < MSORT) { sv[pos] = y / TEMP; si[pos] = cidx[p]; }
            }
        }
    } else {
        for (int i = tid; i < V; i += nth) {
            float y = rowp[i];
            float fb = (y - YLO) * BININV;
            if (fb >= 0.0f) {
                int b = (int)floorf(fb);
                if (b >= NBINS) b = NBINS - 1;
                if (b >= blo) {
                    int pos = atomicAdd(&scount, 1);
                    if (pos < MSORT) { sv[pos] = y / TEMP; si[pos] = i; }
                }
            }
        }
    }
    __syncthreads();
    const int M = min(scount, MSORT);

    if (tid < M) {
        float v = sv[tid]; int ix = si[tid];
        int r = 0;
        for (int j = 0; j < M; ++j) {
            float vj = sv[j]; int ij = si[j];
            if (vj > v || (vj == v && ij < ix)) ++r;
        }
        ssv[r] = v; ssi[r] = ix;
    }
    __syncthreads();

    const float mm = (M > 0) ? ssv[0] : 0.0f;
    if (tid < M) se[tid] = expf(ssv[tid] - mm);
    __syncthreads();

    if (tid == 0) {
        int L = 0;
        if (M > 0) {
            int kk = k_in; if (kk > M) kk = M; if (kk < 1) kk = 1;
            float kth = ssv[kk - 1];
            int Kp = kk;
            while (Kp < M && ssv[Kp] == kth) ++Kp;
            float sum1 = 0.0f;
            for (int i = 0; i < Kp; ++i) sum1 += se[i];
            float cdf = 0.0f;
            for (int i = 0; i < Kp; ++i) {
                if (i > 0 && cdf > TOPP) break;
                L = i + 1;
                cdf += se[i] / sum1;
            }
            float sum2 = 0.0f;
            for (int i = 0; i < L; ++i) sum2 += se[i];
            sum2_sh = sum2;
        } else {
            sum2_sh = 1.0f;
        }
        L_sh = L;
    }
    __syncthreads();
    const int L = L_sh;
    const float sum2 = sum2_sh;

    if (tid < L) {
        int ix = ssi[tid];
        int r = 0;
        for (int j = 0; j < L; ++j) r += (ssi[j] < ix);
        sidx2[r] = ix;
        sq[r] = se[tid] / sum2;
    }
    __syncthreads();

    if (tid == 0) {
        float uu = uvec[row];
        float cum = 0.0f;
        int ans = V;
        for (int i = 0; i < L; ++i) {
            cum += sq[i];
            if (cum > uu) { ans = sidx2[i]; break; }
        }
        out[row] = ans;
    }
}

extern "C" void kernel_launch(void* const* d_in, const int* in_sizes, int n_in,
                              void* d_out, int out_size, void* d_ws, size_t ws_size,
                              hipStream_t stream) {
    const float* logits = (const float*)d_in[0];
    const float* u      = (const float*)d_in[1];
    const int*   topk   = (const int*)d_in[2];
    int*         out    = (int*)d_out;

    const int B = out_size;              // 128 rows
    const int V = in_sizes[0] / B;       // 128000

    // workspace layout: [0,1024) counters; then cy (B*CAP floats); ci (B*CAP ints)
    const size_t req = 1024 + (size_t)B * CAP * 8;
    if (ws_size < req) {
        sampler_mono_kernel<<<B, 1024, 0, stream>>>(logits, u, topk, out, V);
        return;
    }
    int*   cnts = (int*)d_ws;
    float* cy   = (float*)((char*)d_ws + 1024);
    int*   ci   = (int*)((char*)d_ws + 1024 + (size_t)B * CAP * 4);

    hipMemsetAsync(d_ws, 0, 1024, stream);
    scan_kernel<<<B * SLICES, 256, 0, stream>>>(logits, V, cnts, cy, ci);
    select_kernel<<<B, 256, 0, stream>>>(logits, u, topk, cnts, cy, ci, out, V);
}

// Round 3
// 166.865 us; speedup vs baseline: 1.4976x; 1.4976x over previous
//
#include <hip/hip_runtime.h>
#include <math.h>

// Sampler: temperature 0.8, top-k (k=50 input), top-p 0.9, inverse-CDF
// multinomial. B=128 rows, V=128000, fp32 logits -> int32 ids.
//
// R3 structure (atomic-free across blocks):
//  K1 (scan): grid = B x SLICES, 256 thr. Each block scans its slice with 8
//     float4 loads in flight, stages candidates (y >= 11.2, i.e. x >= 14)
//     through a 2KB LDS buffer (LDS atomics only), then writes them to its
//     PRIVATE global segment + plain-stores the count. Zero global atomics,
//     no memset needed.
//  K2 (select): 1 block/row, 256 thr. Prefix over the 16 segment counts,
//     gather candidates, exact rank sort by (x desc, idx asc) ==
//     jnp.argsort(-x) stability, then the serial fp32 softmax / top-p /
//     inverse-CDF tail (identical to the absmax-0 R1/R2 code).
//     Fallback (overflow / count<k / count>1024): exact kth via 32-step
//     binary search on float key bits + rescan. Never fires on this data.

#define SLICES 16
#define SEGCAP 256
#define MSORT  1024

__device__ __forceinline__ unsigned fkey(float y) {
    unsigned b = __float_as_uint(y);
    return (b & 0x80000000u) ? ~b : (b | 0x80000000u);  // y asc -> key asc
}

// ---------------- Kernel 1: segmented streaming candidate scan ----------------
__global__ __launch_bounds__(256)
void scan_kernel(const float* __restrict__ logits, int V,
                 int* __restrict__ scnt,
                 float* __restrict__ cy, int* __restrict__ ci)
{
    constexpr float YTH = 11.2f;   // x = 14.0
    __shared__ float lcy[SEGCAP];
    __shared__ int   lci[SEGCAP];
    __shared__ int   lcnt;

    const int tid = threadIdx.x;
    const int row = blockIdx.x / SLICES;
    const int sl  = blockIdx.x % SLICES;
    if (tid == 0) lcnt = 0;
    __syncthreads();

    const float* rowp = logits + (size_t)row * (size_t)V;
    const float4* rp4 = (const float4*)rowp;
    const int n4  = V >> 2;
    const int per = (n4 + SLICES - 1) / SLICES;
    const int s0  = sl * per;
    const int s1  = min(s0 + per, n4);

    // chunks of 8*256 float4 per block; 8 loads in flight per thread
    for (int cb = s0; cb < s1; cb += 8 * 256) {
        float4 vals[8];
        const int base = cb + tid;
#pragma unroll
        for (int j = 0; j < 8; ++j) {
            int i = base + j * 256;
            vals[j] = (i < s1) ? rp4[i]
                               : make_float4(-1e30f, -1e30f, -1e30f, -1e30f);
        }
#pragma unroll
        for (int j = 0; j < 8; ++j) {
            int i = base + j * 256;
            float ys[4] = {vals[j].x, vals[j].y, vals[j].z, vals[j].w};
#pragma unroll
            for (int c = 0; c < 4; ++c) {
                if (ys[c] >= YTH) {
                    int p = atomicAdd(&lcnt, 1);      // LDS atomic: fast
                    if (p < SEGCAP) { lcy[p] = ys[c]; lci[p] = i * 4 + c; }
                }
            }
        }
    }
    if (sl == SLICES - 1) {  // scalar tail if V % 4 != 0
        for (int i = (n4 << 2) + tid; i < V; i += 256) {
            float y = rowp[i];
            if (y >= YTH) {
                int p = atomicAdd(&lcnt, 1);
                if (p < SEGCAP) { lcy[p] = y; lci[p] = i; }
            }
        }
    }
    __syncthreads();

    const int cnt = lcnt;
    float* cyr = cy + ((size_t)row * SLICES + sl) * SEGCAP;
    int*   cir = ci + ((size_t)row * SLICES + sl) * SEGCAP;
    for (int p = tid; p < min(cnt, SEGCAP); p += 256) {
        cyr[p] = lcy[p];
        cir[p] = lci[p];
    }
    if (tid == 0) scnt[row * SLICES + sl] = cnt;  // cnt > SEGCAP => overflow flag
}

// ---------------- Kernel 2: per-row selection + sampling ----------------
__global__ __launch_bounds__(256)
void select_kernel(const float* __restrict__ logits,
                   const float* __restrict__ uvec,
                   const int* __restrict__ topk_p,
                   const int* __restrict__ scnt,
                   const float* __restrict__ cy, const int* __restrict__ ci,
                   int* __restrict__ out, int V)
{
    constexpr float TEMP = 0.8f;
    constexpr float TOPP = 0.9f;

    __shared__ float sv[MSORT];     // x values
    __shared__ int   si[MSORT];
    __shared__ float ssv[MSORT];    // sorted desc by x (tie: idx asc)
    __shared__ int   ssi[MSORT];
    __shared__ float se[MSORT];     // exp(x - max)
    __shared__ float sq[MSORT];     // final probs, vocab order
    __shared__ int   sidx2[MSORT];
    __shared__ int   segoff[SLICES + 1];
    __shared__ int   bad_sh, scount, cnt_sh;
    __shared__ int   L_sh;
    __shared__ float sum2_sh;

    const int tid = threadIdx.x;
    const int row = blockIdx.x;
    const int nth = blockDim.x;
    const int k_in = *topk_p;

    const float* rowp = logits + (size_t)row * (size_t)V;

    if (tid == 0) {
        int acc = 0, bad = 0;
        for (int s = 0; s < SLICES; ++s) {
            segoff[s] = acc;
            int c = scnt[row * SLICES + s];
            if (c > SEGCAP) bad = 1;
            acc += min(c, SEGCAP);
        }
        segoff[SLICES] = acc;
        bad_sh = bad;
    }
    __syncthreads();

    const int M_all = segoff[SLICES];
    int M;
    if (!bad_sh && M_all >= k_in && M_all <= MSORT) {
        // ---- fast path: gather 16 private segments ----
        for (int s = 0; s < SLICES; ++s) {
            const int off = segoff[s];
            const int c = segoff[s + 1] - off;
            const float* cyr = cy + ((size_t)row * SLICES + s) * SEGCAP;
            const int*   cir = ci + ((size_t)row * SLICES + s) * SEGCAP;
            for (int j = tid; j < c; j += nth) {
                sv[off + j] = cyr[j] / TEMP;
                si[off + j] = cir[j];
            }
        }
        M = M_all;
        __syncthreads();
    } else {
        // ---- exact fallback: kth value via binary search on key bits ----
        if (tid == 0) scount = 0;
        __syncthreads();
        unsigned lo = 0;
        for (int bit = 31; bit >= 0; --bit) {
            unsigned t = lo | (1u << bit);
            int local = 0;
            for (int i = tid; i < V; i += nth) local += (fkey(rowp[i]) >= t);
            if (tid == 0) cnt_sh = 0;
            __syncthreads();
            atomicAdd(&cnt_sh, local);
            __syncthreads();
            if (cnt_sh >= k_in) lo = t;
            __syncthreads();
        }
        for (int i = tid; i < V; i += nth) {
            float y = rowp[i];
            if (fkey(y) >= lo) {
                int p = atomicAdd(&scount, 1);
                if (p < MSORT) { sv[p] = y / TEMP; si[p] = i; }
            }
        }
        __syncthreads();
        M = min(scount, MSORT);
    }

    // ---- exact rank sort: x desc, tie idx asc (matches argsort(-x)) ----
    for (int i = tid; i < M; i += nth) {
        float v = sv[i]; int ix = si[i];
        int r = 0;
        for (int j = 0; j < M; ++j) {
            float vj = sv[j];
            if (vj > v || (vj == v && si[j] < ix)) ++r;
        }
        ssv[r] = v; ssi[r] = ix;
    }
    __syncthreads();

    const float mm = (M > 0) ? ssv[0] : 0.0f;
    for (int i = tid; i < M; i += nth) se[i] = expf(ssv[i] - mm);
    __syncthreads();

    // ---- serial tiny tail: top-k ties, softmax, top-p prefix cut ----
    if (tid == 0) {
        int L = 0;
        if (M > 0) {
            int kk = k_in; if (kk > M) kk = M; if (kk < 1) kk = 1;
            float kth = ssv[kk - 1];
            int Kp = kk;
            while (Kp < M && ssv[Kp] == kth) ++Kp;   // keep ties with kth
            float sum1 = 0.0f;
            for (int i = 0; i < Kp; ++i) sum1 += se[i];
            float cdf = 0.0f;
            for (int i = 0; i < Kp; ++i) {
                if (i > 0 && cdf > TOPP) break;      // remove iff cdf[i-1] > p
                L = i + 1;
                cdf += se[i] / sum1;
            }
            float sum2 = 0.0f;
            for (int i = 0; i < L; ++i) sum2 += se[i];
            sum2_sh = sum2;
        } else {
            sum2_sh = 1.0f;
        }
        L_sh = L;
    }
    __syncthreads();
    const int L = L_sh;
    const float sum2 = sum2_sh;

    // ---- reorder kept entries by vocab index, final probs ----
    if (tid < L) {
        int ix = ssi[tid];
        int r = 0;
        for (int j = 0; j < L; ++j) r += (ssi[j] < ix);
        sidx2[r] = ix;
        sq[r] = se[tid] / sum2;
    }
    __syncthreads();

    // ---- inverse-CDF sample: count(csum <= u) = first idx with cum > u ----
    if (tid == 0) {
        float uu = uvec[row];
        float cum = 0.0f;
        int ans = V;                     // u >= total -> count is V
        for (int i = 0; i < L; ++i) {
            cum += sq[i];
            if (cum > uu) { ans = sidx2[i]; break; }
        }
        out[row] = ans;
    }
}

extern "C" void kernel_launch(void* const* d_in, const int* in_sizes, int n_in,
                              void* d_out, int out_size, void* d_ws, size_t ws_size,
                              hipStream_t stream) {
    const float* logits = (const float*)d_in[0];
    const float* u      = (const float*)d_in[1];
    const int*   topk   = (const int*)d_in[2];
    int*         out    = (int*)d_out;

    const int B = out_size;              // 128 rows
    const int V = in_sizes[0] / B;       // 128000

    // ws layout: scnt (B*SLICES ints) | cy (B*SLICES*SEGCAP floats) | ci (same ints)
    const size_t n_scnt = (size_t)B * SLICES;
    const size_t n_seg  = (size_t)B * SLICES * SEGCAP;
    int*   scnt = (int*)d_ws;
    float* cy   = (float*)((char*)d_ws + n_scnt * 4);
    int*   ci   = (int*)((char*)d_ws + n_scnt * 4 + n_seg * 4);

    scan_kernel<<<B * SLICES, 256, 0, stream>>>(logits, V, scnt, cy, ci);
    select_kernel<<<B, 256, 0, stream>>>(logits, u, topk, scnt, cy, ci, out, V);
}

// Round 4
// 104.468 us; speedup vs baseline: 2.3921x; 1.5973x over previous
//
#include <hip/hip_runtime.h>
#include <math.h>

// Sampler: temperature 0.8, top-k (k=50 input), top-p 0.9, inverse-CDF
// multinomial. B=128 rows, V=128000, fp32 logits -> int32 ids.
//
// K1 (scan): grid = B x SLICES, 256 thr. 8 float4 loads in flight, candidates
//   (y >= 11.2, x >= 14) staged via LDS atomics, written to private global
//   segments + plain count stores. No global atomics.
// K2 (select): 1 block/row, 1024 thr (16 waves for latency hiding).
//   - wave-shuffle prefix over 16 segment counts
//   - parallel gather: one wave per segment (1 global-latency round)
//   - two-tier filter: if #{x >= 16} >= k, sort only those (~88 vs ~327);
//     exact because kept set contains top-k and all kth ties
//   - rank sort (x desc, idx asc == argsort(-x) stability), hand-unrolled x4,
//     padded with -inf sentinels -> batched independent LDS reads
//   - serial fp32 softmax / top-p / inverse-CDF tail: byte-identical
//     semantics to the absmax-0 R1-R3 code
//   - fallback (overflow / count < k): exact kth via binary search on float
//     key bits + rescan. Never fires on this data.

#define SLICES 16
#define SEGCAP 256
#define MSORT  1024

__device__ __forceinline__ unsigned fkey(float y) {
    unsigned b = __float_as_uint(y);
    return (b & 0x80000000u) ? ~b : (b | 0x80000000u);  // y asc -> key asc
}

// ---------------- Kernel 1: segmented streaming candidate scan ----------------
__global__ __launch_bounds__(256)
void scan_kernel(const float* __restrict__ logits, int V,
                 int* __restrict__ scnt,
                 float* __restrict__ cy, int* __restrict__ ci)
{
    constexpr float YTH = 11.2f;   // x = 14.0
    __shared__ float lcy[SEGCAP];
    __shared__ int   lci[SEGCAP];
    __shared__ int   lcnt;

    const int tid = threadIdx.x;
    const int row = blockIdx.x / SLICES;
    const int sl  = blockIdx.x % SLICES;
    if (tid == 0) lcnt = 0;
    __syncthreads();

    const float* rowp = logits + (size_t)row * (size_t)V;
    const float4* rp4 = (const float4*)rowp;
    const int n4  = V >> 2;
    const int per = (n4 + SLICES - 1) / SLICES;
    const int s0  = sl * per;
    const int s1  = min(s0 + per, n4);

    for (int cb = s0; cb < s1; cb += 8 * 256) {
        float4 vals[8];
        const int base = cb + tid;
#pragma unroll
        for (int j = 0; j < 8; ++j) {
            int i = base + j * 256;
            vals[j] = (i < s1) ? rp4[i]
                               : make_float4(-1e30f, -1e30f, -1e30f, -1e30f);
        }
#pragma unroll
        for (int j = 0; j < 8; ++j) {
            int i = base + j * 256;
            float ys[4] = {vals[j].x, vals[j].y, vals[j].z, vals[j].w};
#pragma unroll
            for (int c = 0; c < 4; ++c) {
                if (ys[c] >= YTH) {
                    int p = atomicAdd(&lcnt, 1);      // LDS atomic
                    if (p < SEGCAP) { lcy[p] = ys[c]; lci[p] = i * 4 + c; }
                }
            }
        }
    }
    if (sl == SLICES - 1) {  // scalar tail if V % 4 != 0
        for (int i = (n4 << 2) + tid; i < V; i += 256) {
            float y = rowp[i];
            if (y >= YTH) {
                int p = atomicAdd(&lcnt, 1);
                if (p < SEGCAP) { lcy[p] = y; lci[p] = i; }
            }
        }
    }
    __syncthreads();

    const int cnt = lcnt;
    float* cyr = cy + ((size_t)row * SLICES + sl) * SEGCAP;
    int*   cir = ci + ((size_t)row * SLICES + sl) * SEGCAP;
    for (int p = tid; p < min(cnt, SEGCAP); p += 256) {
        cyr[p] = lcy[p];
        cir[p] = lci[p];
    }
    if (tid == 0) scnt[row * SLICES + sl] = cnt;  // cnt > SEGCAP => overflow flag
}

// ---------------- Kernel 2: per-row selection + sampling ----------------
__global__ __launch_bounds__(1024)
void select_kernel(const float* __restrict__ logits,
                   const float* __restrict__ uvec,
                   const int* __restrict__ topk_p,
                   const int* __restrict__ scnt,
                   const float* __restrict__ cy, const int* __restrict__ ci,
                   int* __restrict__ out, int V)
{
    constexpr float TEMP   = 0.8f;
    constexpr float TOPP   = 0.9f;
    constexpr float XTH2   = 16.0f;   // second-tier threshold in x-space (y=12.8)

    __shared__ float sv[MSORT];     // gathered x values
    __shared__ int   si[MSORT];
    __shared__ float cvv[MSORT];    // compacted values (sort input)
    __shared__ int   cix[MSORT];
    __shared__ float ssv[MSORT];    // sorted desc by x (tie: idx asc)
    __shared__ int   ssi[MSORT];
    __shared__ float se[MSORT];     // exp(x - max)
    __shared__ float sq[MSORT];     // final probs, vocab order
    __shared__ int   sidx2[MSORT];
    __shared__ int   segoff[SLICES + 1];
    __shared__ int   bad_sh, scount, cnt_sh, hi_cnt, cpos;
    __shared__ int   L_sh, M_sh;
    __shared__ float sum2_sh;

    const int tid = threadIdx.x;
    const int row = blockIdx.x;
    const int nth = blockDim.x;
    const int k_in = *topk_p;

    const float* rowp = logits + (size_t)row * (size_t)V;

    // ---- wave 0: segment-count prefix via shuffles (1 global round) ----
    if (tid < 64) {
        int c = (tid < SLICES) ? scnt[row * SLICES + tid] : 0;
        int bad = (tid < SLICES) && (c > SEGCAP);
        int acc = min(c, SEGCAP);
        for (int off = 1; off < SLICES; off <<= 1) {
            int o = __shfl_up(acc, off, 64);
            if (tid >= off) acc += o;
        }
        if (tid < SLICES) segoff[tid + 1] = acc;
        if (tid == 0) segoff[0] = 0;
        unsigned long long bm = __ballot(bad);
        if (tid == 0) bad_sh = (bm != 0ULL);
    }
    if (tid == 0) { hi_cnt = 0; cpos = 0; scount = 0; }
    __syncthreads();

    const int M_all = segoff[SLICES];
    int M;
    if (!bad_sh && M_all >= k_in && M_all <= MSORT) {
        // ---- parallel gather: one wave per segment ----
        {
            const int s  = tid >> 6;          // 0..15 (SLICES*64 == 1024)
            const int j0 = tid & 63;
            const int off = segoff[s];
            const int c   = segoff[s + 1] - off;
            const float* cyr = cy + ((size_t)row * SLICES + s) * SEGCAP;
            const int*   cir = ci + ((size_t)row * SLICES + s) * SEGCAP;
            for (int j = j0; j < c; j += 64) {
                sv[off + j] = cyr[j] / TEMP;
                si[off + j] = cir[j];
            }
        }
        __syncthreads();

        // ---- two-tier: count x >= XTH2 ----
        {
            int pred = (tid < M_all) && (sv[tid] >= XTH2);
            unsigned long long bm = __ballot(pred);
            if ((tid & 63) == 0 && bm) atomicAdd(&hi_cnt, __popcll(bm));
        }
        __syncthreads();

        // ---- compact (order irrelevant; sort is a total order) ----
        const float thr = (hi_cnt >= k_in) ? XTH2 : -1e38f;
        if (tid < M_all && sv[tid] >= thr) {
            int p = atomicAdd(&cpos, 1);
            cvv[p] = sv[tid]; cix[p] = si[tid];
        }
        __syncthreads();
        M = cpos;
    } else {
        // ---- exact fallback: kth via binary search on float key bits ----
        unsigned lo = 0;
        for (int bit = 31; bit >= 0; --bit) {
            unsigned t = lo | (1u << bit);
            int local = 0;
            for (int i = tid; i < V; i += nth) local += (fkey(rowp[i]) >= t);
            if (tid == 0) cnt_sh = 0;
            __syncthreads();
            atomicAdd(&cnt_sh, local);
            __syncthreads();
            if (cnt_sh >= k_in) lo = t;
            __syncthreads();
        }
        for (int i = tid; i < V; i += nth) {
            float y = rowp[i];
            if (fkey(y) >= lo) {
                int p = atomicAdd(&scount, 1);
                if (p < MSORT) { cvv[p] = y / TEMP; cix[p] = i; }
            }
        }
        __syncthreads();
        M = min(scount, MSORT);
    }
    if (tid == 0) M_sh = M;
    __syncthreads();
    M = M_sh;

    // ---- pad to multiple of 4 with -inf sentinels (branch-free inner loop) --
    const int Mpad = (M + 3) & ~3;
    if (tid >= M && tid < Mpad) { cvv[tid] = -1e38f; cix[tid] = 0x7fffffff; }
    __syncthreads();

    // ---- rank sort: x desc, tie idx asc (matches argsort(-x)); unrolled x4 --
    if (tid < M) {
        const float v = cvv[tid]; const int ix = cix[tid];
        int r = 0;
        for (int j = 0; j < Mpad; j += 4) {
            float v0 = cvv[j],     v1 = cvv[j + 1];
            float v2 = cvv[j + 2], v3 = cvv[j + 3];
            int   i0 = cix[j],     i1 = cix[j + 1];
            int   i2 = cix[j + 2], i3 = cix[j + 3];
            r += (v0 > v || (v0 == v && i0 < ix));
            r += (v1 > v || (v1 == v && i1 < ix));
            r += (v2 > v || (v2 == v && i2 < ix));
            r += (v3 > v || (v3 == v && i3 < ix));
        }
        ssv[r] = v; ssi[r] = ix;
    }
    __syncthreads();

    const float mm = (M > 0) ? ssv[0] : 0.0f;
    if (tid < M) se[tid] = expf(ssv[tid] - mm);
    __syncthreads();

    // ---- serial tiny tail: top-k ties, softmax, top-p prefix cut ----
    if (tid == 0) {
        int L = 0;
        if (M > 0) {
            int kk = k_in; if (kk > M) kk = M; if (kk < 1) kk = 1;
            float kth = ssv[kk - 1];
            int Kp = kk;
            while (Kp < M && ssv[Kp] == kth) ++Kp;   // keep ties with kth
            float sum1 = 0.0f;
            for (int i = 0; i < Kp; ++i) sum1 += se[i];
            float cdf = 0.0f;
            for (int i = 0; i < Kp; ++i) {
                if (i > 0 && cdf > TOPP) break;      // remove iff cdf[i-1] > p
                L = i + 1;
                cdf += se[i] / sum1;
            }
            float sum2 = 0.0f;
            for (int i = 0; i < L; ++i) sum2 += se[i];
            sum2_sh = sum2;
        } else {
            sum2_sh = 1.0f;
        }
        L_sh = L;
    }
    __syncthreads();
    const int L = L_sh;
    const float sum2 = sum2_sh;

    // ---- reorder kept entries by vocab index, final probs ----
    if (tid < L) {
        int ix = ssi[tid];
        int r = 0;
        for (int j = 0; j < L; ++j) r += (ssi[j] < ix);
        sidx2[r] = ix;
        sq[r] = se[tid] / sum2;
    }
    __syncthreads();

    // ---- inverse-CDF sample: count(csum <= u) = first idx with cum > u ----
    if (tid == 0) {
        float uu = uvec[row];
        float cum = 0.0f;
        int ans = V;                     // u >= total -> count is V
        for (int i = 0; i < L; ++i) {
            cum += sq[i];
            if (cum > uu) { ans = sidx2[i]; break; }
        }
        out[row] = ans;
    }
}

extern "C" void kernel_launch(void* const* d_in, const int* in_sizes, int n_in,
                              void* d_out, int out_size, void* d_ws, size_t ws_size,
                              hipStream_t stream) {
    const float* logits = (const float*)d_in[0];
    const float* u      = (const float*)d_in[1];
    const int*   topk   = (const int*)d_in[2];
    int*         out    = (int*)d_out;

    const int B = out_size;              // 128 rows
    const int V = in_sizes[0] / B;       // 128000

    // ws layout: scnt (B*SLICES ints) | cy (B*SLICES*SEGCAP floats) | ci (ints)
    const size_t n_scnt = (size_t)B * SLICES;
    const size_t n_seg  = (size_t)B * SLICES * SEGCAP;
    int*   scnt = (int*)d_ws;
    float* cy   = (float*)((char*)d_ws + n_scnt * 4);
    int*   ci   = (int*)((char*)d_ws + n_scnt * 4 + n_seg * 4);

    scan_kernel<<<B * SLICES, 256, 0, stream>>>(logits, V, scnt, cy, ci);
    select_kernel<<<B, 1024, 0, stream>>>(logits, u, topk, scnt, cy, ci, out, V);
}